// Round 9
// baseline (341.950 us; speedup 1.0000x reference)
//
#include <hip/hip_runtime.h>
#include <hip/hip_bf16.h>

#define Bc 4
#define Tc 16
#define Nc 1024
#define Ec 16384
#define FIN 128
#define Hc 256
#define FFc 1024
#define NHc 8
#define Lc 2
#define HDc 32
#define Gc 64
#define EPSc 1e-5f

typedef __bf16 v8bf __attribute__((ext_vector_type(8)));
typedef float v4f __attribute__((ext_vector_type(4)));

// ---------------- W pack: Wcat[256][256]=[Wl1;Wr1] -> MFMA B-frag order, bf16 hi+lo ----------------
__global__ void pack_w_kernel(const float* __restrict__ Wl, const float* __restrict__ Wr,
                              __bf16* __restrict__ pH, __bf16* __restrict__ pL) {
    int bid = blockIdx.x;            // 0..127 = kc*16+nt
    int t = threadIdx.x;             // 512
    int lane = t >> 3, j = t & 7;
    int kc = bid >> 4, nt = bid & 15;
    int k = kc * 32 + ((lane >> 4) << 3) + j;
    int n = nt * 16 + (lane & 15);
    float w = (k < 128) ? Wl[(size_t)k * Hc + n] : Wr[(size_t)(k - 128) * Hc + n];
    __bf16 hi = (__bf16)w;
    __bf16 lo = (__bf16)(w - (float)hi);
    pH[bid * 512 + t] = hi;
    pL[bid * 512 + t] = lo;
}

// ---------------- per graph: invdeg, cw, CSR(off,elist ushort), zero uv. 1024 thr ----------------
__global__ __launch_bounds__(1024) void csr_kernel(
        const int* __restrict__ ei, float* __restrict__ invdeg, float* __restrict__ cw,
        int* __restrict__ off, unsigned short* __restrict__ elist, float* __restrict__ uv) {
    __shared__ int degs[Nc];
    __shared__ float inv[Nc];
    __shared__ float cl[Nc];
    __shared__ int wsum[16];
    int g = blockIdx.x, t = threadIdx.x;   // 1024 threads
    const int* src = ei + (size_t)g * 2 * Ec;
    const int* dst = src + Ec;
    if (t < 512) uv[g * 512 + t] = 0.f;
    degs[t] = 0; cl[t] = 0.f;
    __syncthreads();
    for (int e = t; e < Ec; e += 1024) atomicAdd(&degs[dst[e] & (Nc - 1)], 1);
    __syncthreads();
    float iv = 1.0f / fmaxf((float)degs[t], 1.0f);
    inv[t] = iv;
    invdeg[g * Nc + t] = iv;
    __syncthreads();
    for (int e = t; e < Ec; e += 1024) atomicAdd(&cl[src[e] & (Nc - 1)], inv[dst[e] & (Nc - 1)]);
    __syncthreads();
    cw[g * Nc + t] = cl[t];
    // wave-level inclusive scan of degs (16 waves of 64)
    int own = degs[t];
    int lane = t & 63, wv = t >> 6;
    int val = own;
#pragma unroll
    for (int ofs = 1; ofs < 64; ofs <<= 1) {
        int v = __shfl_up(val, ofs, 64);
        if (lane >= ofs) val += v;
    }
    if (lane == 63) wsum[wv] = val;
    __syncthreads();
    if (wv == 0 && lane < 16) {
        int wval = wsum[lane];
#pragma unroll
        for (int ofs = 1; ofs < 16; ofs <<= 1) {
            int v = __shfl_up(wval, ofs, 64);
            if (lane >= ofs) wval += v;
        }
        wsum[lane] = wval;
    }
    __syncthreads();
    int incl = val + ((wv > 0) ? wsum[wv - 1] : 0);
    int excl = incl - own;
    off[g * 1032 + t] = excl;
    if (t == 1023) off[g * 1032 + Nc] = incl;
    degs[t] = excl;                      // cursors
    __syncthreads();
    for (int e = t; e < Ec; e += 1024) {
        int d = dst[e] & (Nc - 1);
        int slot = atomicAdd(&degs[d], 1);
        elist[(size_t)g * Ec + slot] = (unsigned short)(src[e] & (Nc - 1));
    }
}

// ---------------- SAGE layer1 + reduce: XCD-swizzled, gather -> MFMA hi/lo -> u,v ----------------
// Split into 4 launches of 512 blocks (c0 = cc offset) for profiling visibility; outputs disjoint.
__global__ __launch_bounds__(512) void sage_kernel(
        const float* __restrict__ x, const unsigned short* __restrict__ elist,
        const int* __restrict__ off, const float* __restrict__ invdeg,
        const float* __restrict__ cw, const __bf16* __restrict__ pH,
        const __bf16* __restrict__ pL, const float* __restrict__ bias,
        float* __restrict__ uv, int c0) {
    __shared__ float aggL[32 * 132];     // stride 132 (4-float row skew)
    __shared__ float xL[32 * 132];
    __shared__ float lu[256], lv[256];
    int tid = threadIdx.x;
    int bid = blockIdx.x;
    // XCD swizzle: bid = cc*64 + g  => all blocks of graph g share bid%8 (same XCD L2)
    int g = bid & 63, cc = c0 + (bid >> 6), r0 = cc * 32;
    const unsigned short* el = elist + (size_t)g * Ec;
    const float* xg = x + (size_t)g * Nc * FIN;
    if (tid < 256) { lu[tid] = 0.f; lv[tid] = 0.f; }

    // phase A: one (row, 8-dim chunk) per thread, edge loop batched by 8
    {
        int lr = tid >> 4, ch = tid & 15;
        int n = r0 + lr;
        int o0 = off[g * 1032 + n], o1 = off[g * 1032 + n + 1];
        float4 a0 = make_float4(0.f, 0.f, 0.f, 0.f);
        float4 a1 = make_float4(0.f, 0.f, 0.f, 0.f);
        const float* xc = xg + ch * 8;
        int e = o0;
        for (; e + 8 <= o1; e += 8) {
            int s[8];
#pragma unroll
            for (int j = 0; j < 8; ++j) s[j] = el[e + j];
            float4 v0[8], v1[8];
#pragma unroll
            for (int j = 0; j < 8; ++j) {
                const float4* xp = (const float4*)(xc + (size_t)s[j] * FIN);
                v0[j] = xp[0]; v1[j] = xp[1];
            }
#pragma unroll
            for (int j = 0; j < 8; ++j) {
                a0.x += v0[j].x; a0.y += v0[j].y; a0.z += v0[j].z; a0.w += v0[j].w;
                a1.x += v1[j].x; a1.y += v1[j].y; a1.z += v1[j].z; a1.w += v1[j].w;
            }
        }
        for (; e < o1; ++e) {
            const float4* xp = (const float4*)(xc + (size_t)el[e] * FIN);
            float4 v0 = xp[0], v1 = xp[1];
            a0.x += v0.x; a0.y += v0.y; a0.z += v0.z; a0.w += v0.w;
            a1.x += v1.x; a1.y += v1.y; a1.z += v1.z; a1.w += v1.w;
        }
        float iv = invdeg[g * Nc + n];
        float* dp = &aggL[lr * 132 + ch * 8];
        dp[0] = a0.x * iv; dp[1] = a0.y * iv; dp[2] = a0.z * iv; dp[3] = a0.w * iv;
        dp[4] = a1.x * iv; dp[5] = a1.y * iv; dp[6] = a1.z * iv; dp[7] = a1.w * iv;
    }
    // stage own-row x tile (float4)
    for (int i = tid; i < 1024; i += 512) {
        int lr = i >> 5, kq = i & 31;
        *(float4*)&xL[lr * 132 + kq * 4] = *(const float4*)&xg[(size_t)(r0 + lr) * FIN + kq * 4];
    }
    __syncthreads();

    // phase B: 8 waves: mt = w&1 (16-row tile), nh = w>>1 (4 n-tiles each)
    int w = tid >> 6, lane = tid & 63, quad = lane >> 4;
    int mt = w & 1, nh = w >> 1;
    int lrow = mt * 16 + (lane & 15);
    v4f acc[4];
#pragma unroll
    for (int i = 0; i < 4; ++i) acc[i] = (v4f)0.f;
    for (int kc = 0; kc < 8; ++kc) {
        const float* ap = (kc < 4) ? &aggL[lrow * 132 + kc * 32 + quad * 8]
                                   : &xL[lrow * 132 + (kc - 4) * 32 + quad * 8];
        float4 f0 = *(const float4*)ap;
        float4 f1 = *(const float4*)(ap + 4);
        float av[8] = {f0.x, f0.y, f0.z, f0.w, f1.x, f1.y, f1.z, f1.w};
        v8bf aH, aL;
#pragma unroll
        for (int j = 0; j < 8; ++j) {
            __bf16 hb = (__bf16)av[j];
            aH[j] = hb;
            aL[j] = (__bf16)(av[j] - (float)hb);
        }
#pragma unroll
        for (int i = 0; i < 4; ++i) {
            int nt = nh * 4 + i;
            v8bf bH = *(const v8bf*)(pH + ((size_t)(kc * 16 + nt) * 64 + lane) * 8);
            v8bf bL = *(const v8bf*)(pL + ((size_t)(kc * 16 + nt) * 64 + lane) * 8);
            acc[i] = __builtin_amdgcn_mfma_f32_16x16x32_bf16(aH, bH, acc[i], 0, 0, 0);
            acc[i] = __builtin_amdgcn_mfma_f32_16x16x32_bf16(aL, bH, acc[i], 0, 0, 0);
            acc[i] = __builtin_amdgcn_mfma_f32_16x16x32_bf16(aH, bL, acc[i], 0, 0, 0);
        }
    }

    // epilogue: bias+relu; u (cw-weighted) / v column sums. C/D: col=lane&15, row=quad*4+r
    float c4[4];
    int nb = g * Nc + r0 + mt * 16 + quad * 4;
#pragma unroll
    for (int r = 0; r < 4; ++r) c4[r] = cw[nb + r];
#pragma unroll
    for (int i = 0; i < 4; ++i) {
        int col = (nh * 4 + i) * 16 + (lane & 15);
        float bcol = bias[col];
        float su = 0.f, sv = 0.f;
#pragma unroll
        for (int r = 0; r < 4; ++r) {
            float val = fmaxf(acc[i][r] + bcol, 0.f);
            sv += val;
            su += c4[r] * val;
        }
        su += __shfl_xor(su, 16); sv += __shfl_xor(sv, 16);
        su += __shfl_xor(su, 32); sv += __shfl_xor(sv, 32);
        if (quad == 0) { atomicAdd(&lu[col], su); atomicAdd(&lv[col], sv); }
    }
    __syncthreads();
    if (tid < 256) {
        atomicAdd(&uv[g * 512 + tid], lu[tid]);
        atomicAdd(&uv[g * 512 + 256 + tid], lv[tid]);
    }
}

// ---------------- emb = u/N @ Wl2 + bl2 + v/N @ Wr2. 512 thr, K split 2 ----------------
__global__ __launch_bounds__(512) void emb_kernel(
        const float* __restrict__ uv, const float* __restrict__ Wl2,
        const float* __restrict__ bl2, const float* __restrict__ Wr2,
        float* __restrict__ h) {
    __shared__ float s[512];
    __shared__ float r2[512];
    int g = blockIdx.x, tid = threadIdx.x;
    s[tid] = uv[g * 512 + tid] * (1.0f / Nc);
    __syncthreads();
    int col = tid & 255, p = tid >> 8;
    float val = 0.f;
    if (p == 0) { for (int k = 0; k < 256; ++k) val += s[k] * Wl2[(size_t)k * Hc + col]; }
    else        { for (int k = 0; k < 256; ++k) val += s[256 + k] * Wr2[(size_t)k * Hc + col]; }
    r2[tid] = val;
    __syncthreads();
    if (tid < 256) h[g * Hc + tid] = bl2[tid] + r2[tid] + r2[tid + 256];
}

// ---------------- qkv: token x seg, 512 thr, K split 2 ----------------
__global__ __launch_bounds__(512) void qkv_kernel(
        const float* __restrict__ h, const float* __restrict__ Wqkv,
        const float* __restrict__ bqkv, float* __restrict__ qkv, int l) {
    __shared__ float hr[256];
    __shared__ float r2[512];
    int bid = blockIdx.x;            // 64 tokens * 3 segs
    int gi = bid / 3, seg = bid % 3;
    int tid = threadIdx.x;
    if (tid < 256) hr[tid] = h[gi * Hc + tid];
    __syncthreads();
    int col = seg * 256 + (tid & 255);
    int half = tid >> 8;
    const float* W = Wqkv + (size_t)l * Hc * 768;
    float val = 0.f;
    int k0 = half * 128;
    for (int k = 0; k < 128; ++k) val += hr[k0 + k] * W[(size_t)(k0 + k) * 768 + col];
    r2[tid] = val;
    __syncthreads();
    if (tid < 256) qkv[gi * 768 + col] = bqkv[(size_t)l * 768 + col] + r2[tid] + r2[tid + 256];
}

// ---------------- fused attn+proj+ln1+ffn1+ffn2+ln2(+fc): per token, 1024 thr ----------------
#define KVS 516
__global__ __launch_bounds__(1024) void rest_kernel(
        const float* __restrict__ hin, float* __restrict__ hout,
        const float* __restrict__ qkvg,
        const float* __restrict__ Wo, const float* __restrict__ bo,
        const float* __restrict__ s1, const float* __restrict__ b1ln,
        const float* __restrict__ W1, const float* __restrict__ bf1,
        const float* __restrict__ W2, const float* __restrict__ bf2,
        const float* __restrict__ s2, const float* __restrict__ b2ln,
        const float* __restrict__ fcW, const float* __restrict__ fcb,
        float* __restrict__ out, int l, int last) {
    __shared__ float kv[16 * KVS];
    __shared__ float q[256];
    __shared__ float sc[8][17];
    __shared__ float ctx[256];
    __shared__ float r2[512];
    __shared__ float red[256];
    __shared__ float rF[2048];
    __shared__ float fLs[1024];
    __shared__ float h1L[256];
    int t = blockIdx.x, tid = threadIdx.x;
    int b = t >> 4;
    const float* qb = qkvg + (size_t)(b * 16) * 768;
    for (int i = tid; i < 8192; i += 1024) {
        int j = i >> 9, d = i & 511;
        kv[j * KVS + d] = qb[(size_t)j * 768 + 256 + d];
    }
    if (tid < 256) q[tid] = qkvg[(size_t)t * 768 + tid];
    __syncthreads();
    if (tid < 128) {
        int hd = tid >> 4, jj = tid & 15;
        float s = 0.f;
#pragma unroll
        for (int d = 0; d < 32; ++d) s += q[hd * 32 + d] * kv[jj * KVS + hd * 32 + d];
        sc[hd][jj] = s * 0.17677669529663687f;
    }
    __syncthreads();
    if (tid < 8) {
        float m = sc[tid][0];
        for (int j = 1; j < 16; ++j) m = fmaxf(m, sc[tid][j]);
        float e[16], sum = 0.f;
        for (int j = 0; j < 16; ++j) { e[j] = expf(sc[tid][j] - m); sum += e[j]; }
        float inv = 1.0f / sum;
        for (int j = 0; j < 16; ++j) sc[tid][j] = e[j] * inv;
    }
    __syncthreads();
    if (tid < 256) {
        int hd = tid >> 5, d = tid & 31;
        float o = 0.f;
#pragma unroll
        for (int j = 0; j < 16; ++j) o += sc[hd][j] * kv[j * KVS + 256 + hd * 32 + d];
        ctx[tid] = o;
    }
    __syncthreads();
    // proj: K split 2
    if (tid < 512) {
        int col = tid & 255, half = tid >> 8;
        const float* W = Wo + (size_t)l * 65536;
        float pv = 0.f;
        int k0 = half * 128;
        for (int k = 0; k < 128; ++k) pv += ctx[k0 + k] * W[(size_t)(k0 + k) * 256 + col];
        r2[tid] = pv;
    }
    __syncthreads();
    float val = 0.f;
    if (tid < 256) {
        val = hin[(size_t)t * 256 + tid] + bo[(size_t)l * 256 + tid] + r2[tid] + r2[tid + 256];
        red[tid] = val;
    }
    __syncthreads();
    for (int s = 128; s > 0; s >>= 1) { if (tid < s) red[tid] += red[tid + s]; __syncthreads(); }
    float m1 = red[0] * (1.0f / 256.0f);
    __syncthreads();
    float d1 = val - m1;
    if (tid < 256) red[tid] = d1 * d1;
    __syncthreads();
    for (int s = 128; s > 0; s >>= 1) { if (tid < s) red[tid] += red[tid + s]; __syncthreads(); }
    float v1 = red[0] * (1.0f / 256.0f);
    if (tid < 256)
        h1L[tid] = d1 * rsqrtf(v1 + EPSc) * s1[(size_t)l * 256 + tid] + b1ln[(size_t)l * 256 + tid];
    __syncthreads();
    // ffn1 (K split 2, 4 colgroups)
#pragma unroll
    for (int pass = 0; pass < 2; ++pass) {
        int pid = pass * 1024 + tid;
        int cg = pid >> 9, ch = pid & 511;
        int col = cg * 256 + (ch & 255), half = ch >> 8;
        const float* W = W1 + (size_t)l * 262144;
        float v = 0.f;
        int k0 = half * 128;
        for (int k = 0; k < 128; ++k) v += h1L[k0 + k] * W[(size_t)(k0 + k) * 1024 + col];
        rF[pid] = v;
    }
    __syncthreads();
    {
        int cg = tid >> 8, c8 = tid & 255;
        fLs[tid] = fmaxf(bf1[(size_t)l * 1024 + tid] + rF[cg * 512 + c8] + rF[cg * 512 + 256 + c8], 0.f);
    }
    __syncthreads();
    // ffn2 (K split 4)
    {
        int col = tid & 255, kq = tid >> 8;
        const float* W = W2 + (size_t)l * 262144;
        float p = 0.f;
        int k0 = kq * 256;
        for (int k = 0; k < 256; ++k) p += fLs[k0 + k] * W[(size_t)(k0 + k) * 256 + col];
        rF[tid] = p;
    }
    __syncthreads();
    float val2 = 0.f;
    if (tid < 256) {
        val2 = h1L[tid] + bf2[(size_t)l * 256 + tid]
             + rF[tid] + rF[tid + 256] + rF[tid + 512] + rF[tid + 768];
        red[tid] = val2;
    }
    __syncthreads();
    for (int s = 128; s > 0; s >>= 1) { if (tid < s) red[tid] += red[tid + s]; __syncthreads(); }
    float m2 = red[0] * (1.0f / 256.0f);
    __syncthreads();
    float d2 = (tid < 256) ? (val2 - m2) : 0.f;
    if (tid < 256) red[tid] = d2 * d2;
    __syncthreads();
    for (int s = 128; s > 0; s >>= 1) { if (tid < s) red[tid] += red[tid + s]; __syncthreads(); }
    float var2 = red[0] * (1.0f / 256.0f);
    float hn = 0.f;
    if (tid < 256) {
        hn = d2 * rsqrtf(var2 + EPSc) * s2[(size_t)l * 256 + tid] + b2ln[(size_t)l * 256 + tid];
        hout[(size_t)t * 256 + tid] = hn;
    }
    if (last && (t & 15) == 15) {
        __syncthreads();
        if (tid < 256) red[tid] = hn;
        __syncthreads();
        if (tid < 10) {
            int bb = t >> 4;
            float fv = fcb[tid];
            for (int k = 0; k < 256; ++k) fv += red[k] * fcW[(size_t)k * 10 + tid];
            out[bb * 10 + tid] = fv;
        }
    }
}

extern "C" void kernel_launch(void* const* d_in, const int* in_sizes, int n_in,
                              void* d_out, int out_size, void* d_ws, size_t ws_size,
                              hipStream_t stream) {
    (void)in_sizes; (void)n_in; (void)out_size; (void)ws_size;
    const float* x    = (const float*)d_in[0];
    const int*   ei   = (const int*)d_in[1];
    const float* s1Wl = (const float*)d_in[2];
    const float* s1bl = (const float*)d_in[3];
    const float* s1Wr = (const float*)d_in[4];
    const float* s2Wl = (const float*)d_in[5];
    const float* s2bl = (const float*)d_in[6];
    const float* s2Wr = (const float*)d_in[7];
    const float* Wqkv = (const float*)d_in[8];
    const float* bqkv = (const float*)d_in[9];
    const float* Wo   = (const float*)d_in[10];
    const float* bo   = (const float*)d_in[11];
    const float* ln1s = (const float*)d_in[12];
    const float* ln1b = (const float*)d_in[13];
    const float* W1   = (const float*)d_in[14];
    const float* b1   = (const float*)d_in[15];
    const float* W2   = (const float*)d_in[16];
    const float* b2   = (const float*)d_in[17];
    const float* ln2s = (const float*)d_in[18];
    const float* ln2b = (const float*)d_in[19];
    const float* fcW  = (const float*)d_in[20];
    const float* fcb  = (const float*)d_in[21];

    // workspace layout (total ~3.6 MB)
    char* ws = (char*)d_ws;
    __bf16*         packWH = (__bf16*)(ws + 0);          // 131072
    __bf16*         packWL = (__bf16*)(ws + 131072);     // 131072
    float*          invdeg = (float*)(ws + 262144);      // 262144
    float*          cw     = (float*)(ws + 524288);      // 262144
    int*            off    = (int*)(ws + 786432);        // 264192
    unsigned short* elist  = (unsigned short*)(ws + 1050624); // 2097152
    float*          uv     = (float*)(ws + 3147776);     // 131072
    float*          h      = (float*)(ws + 3278848);     // 65536
    float*          h2     = (float*)(ws + 3344384);     // 65536
    float*          qkvg   = (float*)(ws + 3409920);     // 196608
                                                         // end = 3606528

    pack_w_kernel<<<128, 512, 0, stream>>>(s1Wl, s1Wr, packWH, packWL);
    csr_kernel<<<Gc, 1024, 0, stream>>>(ei, invdeg, cw, off, elist, uv);
    sage_kernel<<<Gc * 8, 512, 0, stream>>>(x, elist, off, invdeg, cw, packWH, packWL, s1bl, uv, 0);
    sage_kernel<<<Gc * 8, 512, 0, stream>>>(x, elist, off, invdeg, cw, packWH, packWL, s1bl, uv, 8);
    sage_kernel<<<Gc * 8, 512, 0, stream>>>(x, elist, off, invdeg, cw, packWH, packWL, s1bl, uv, 16);
    sage_kernel<<<Gc * 8, 512, 0, stream>>>(x, elist, off, invdeg, cw, packWH, packWL, s1bl, uv, 24);
    emb_kernel<<<Gc, 512, 0, stream>>>(uv, s2Wl, s2bl, s2Wr, h);
    qkv_kernel<<<Gc * 3, 512, 0, stream>>>(h, Wqkv, bqkv, qkvg, 0);
    rest_kernel<<<Gc, 1024, 0, stream>>>(h, h2, qkvg, Wo, bo, ln1s, ln1b,
                                         W1, b1, W2, b2, ln2s, ln2b, fcW, fcb,
                                         (float*)d_out, 0, 0);
    qkv_kernel<<<Gc * 3, 512, 0, stream>>>(h2, Wqkv, bqkv, qkvg, 1);
    rest_kernel<<<Gc, 1024, 0, stream>>>(h2, h, qkvg, Wo, bo, ln1s, ln1b,
                                         W1, b1, W2, b2, ln2s, ln2b, fcW, fcb,
                                         (float*)d_out, 1, 1);
}

// Round 10
// 312.929 us; speedup vs baseline: 1.0927x; 1.0927x over previous
//
#include <hip/hip_runtime.h>
#include <hip/hip_bf16.h>

#define Bc 4
#define Tc 16
#define Nc 1024
#define Ec 16384
#define FIN 128
#define Hc 256
#define FFc 1024
#define NHc 8
#define Lc 2
#define HDc 32
#define Gc 64
#define EPSc 1e-5f

typedef __bf16 v8bf __attribute__((ext_vector_type(8)));
typedef float v4f __attribute__((ext_vector_type(4)));

// Exact-tree block reduce over red[0..255]: identical adds/order to the original
// for(s=128..1){red[tid]+=red[tid+s];__syncthreads();} loop. In-wave tail via shfl_down
// (lane i at step s reads lane i+s's value == original red[i+s] state; induction => bit-exact).
#define TREE256(red, tid, OUTVAR) {                                             \
    if ((tid) < 128) red[tid] += red[(tid) + 128];                              \
    __syncthreads();                                                            \
    if ((tid) < 64) {                                                           \
        float v_ = red[tid] + red[(tid) + 64];                                  \
        v_ += __shfl_down(v_, 32);                                              \
        v_ += __shfl_down(v_, 16);                                              \
        v_ += __shfl_down(v_, 8);                                               \
        v_ += __shfl_down(v_, 4);                                               \
        v_ += __shfl_down(v_, 2);                                               \
        v_ += __shfl_down(v_, 1);                                               \
        if ((tid) == 0) red[0] = v_;                                            \
    }                                                                           \
    __syncthreads();                                                            \
    OUTVAR = red[0];                                                            \
}

// ---------------- W pack: Wcat[256][256]=[Wl1;Wr1] -> MFMA B-frag order, bf16 hi+lo ----------------
__global__ void pack_w_kernel(const float* __restrict__ Wl, const float* __restrict__ Wr,
                              __bf16* __restrict__ pH, __bf16* __restrict__ pL) {
    int bid = blockIdx.x;            // 0..127 = kc*16+nt
    int t = threadIdx.x;             // 512
    int lane = t >> 3, j = t & 7;
    int kc = bid >> 4, nt = bid & 15;
    int k = kc * 32 + ((lane >> 4) << 3) + j;
    int n = nt * 16 + (lane & 15);
    float w = (k < 128) ? Wl[(size_t)k * Hc + n] : Wr[(size_t)(k - 128) * Hc + n];
    __bf16 hi = (__bf16)w;
    __bf16 lo = (__bf16)(w - (float)hi);
    pH[bid * 512 + t] = hi;
    pL[bid * 512 + t] = lo;
}

// ---------------- per graph: invdeg, cw, CSR(off,elist ushort), zero uv. 1024 thr ----------------
// Edge stream staged ONCE into registers (16 dst + 16 src per thread), reused across phases.
__global__ __launch_bounds__(1024) void csr_kernel(
        const int* __restrict__ ei, float* __restrict__ invdeg, float* __restrict__ cw,
        int* __restrict__ off, unsigned short* __restrict__ elist, float* __restrict__ uv) {
    __shared__ int degs[Nc];
    __shared__ float inv[Nc];
    __shared__ float cl[Nc];
    __shared__ int wsum[16];
    int g = blockIdx.x, t = threadIdx.x;   // 1024 threads; Ec/1024 = 16 edges/thread
    const int* src = ei + (size_t)g * 2 * Ec;
    const int* dst = src + Ec;
    int ld[16], ls[16];
#pragma unroll
    for (int i = 0; i < 16; ++i) ld[i] = dst[t + i * 1024] & (Nc - 1);
#pragma unroll
    for (int i = 0; i < 16; ++i) ls[i] = src[t + i * 1024] & (Nc - 1);
    if (t < 512) uv[g * 512 + t] = 0.f;
    degs[t] = 0; cl[t] = 0.f;
    __syncthreads();
#pragma unroll
    for (int i = 0; i < 16; ++i) atomicAdd(&degs[ld[i]], 1);
    __syncthreads();
    float iv = 1.0f / fmaxf((float)degs[t], 1.0f);
    inv[t] = iv;
    invdeg[g * Nc + t] = iv;
    __syncthreads();
#pragma unroll
    for (int i = 0; i < 16; ++i) atomicAdd(&cl[ls[i]], inv[ld[i]]);
    __syncthreads();
    cw[g * Nc + t] = cl[t];
    // wave-level inclusive scan of degs (16 waves of 64)
    int own = degs[t];
    int lane = t & 63, wv = t >> 6;
    int val = own;
#pragma unroll
    for (int ofs = 1; ofs < 64; ofs <<= 1) {
        int v = __shfl_up(val, ofs, 64);
        if (lane >= ofs) val += v;
    }
    if (lane == 63) wsum[wv] = val;
    __syncthreads();
    if (wv == 0 && lane < 16) {
        int wval = wsum[lane];
#pragma unroll
        for (int ofs = 1; ofs < 16; ofs <<= 1) {
            int v = __shfl_up(wval, ofs, 64);
            if (lane >= ofs) wval += v;
        }
        wsum[lane] = wval;
    }
    __syncthreads();
    int incl = val + ((wv > 0) ? wsum[wv - 1] : 0);
    int excl = incl - own;
    off[g * 1032 + t] = excl;
    if (t == 1023) off[g * 1032 + Nc] = incl;
    degs[t] = excl;                      // cursors
    __syncthreads();
#pragma unroll
    for (int i = 0; i < 16; ++i) {
        int slot = atomicAdd(&degs[ld[i]], 1);
        elist[(size_t)g * Ec + slot] = (unsigned short)ls[i];
    }
}

// ---------------- SAGE layer1 + reduce: XCD-swizzled, gather -> MFMA hi/lo -> u,v ----------------
__global__ __launch_bounds__(512) void sage_kernel(
        const float* __restrict__ x, const unsigned short* __restrict__ elist,
        const int* __restrict__ off, const float* __restrict__ invdeg,
        const float* __restrict__ cw, const __bf16* __restrict__ pH,
        const __bf16* __restrict__ pL, const float* __restrict__ bias,
        float* __restrict__ uv) {
    __shared__ float aggL[32 * 132];     // stride 132 (4-float row skew)
    __shared__ float xL[32 * 132];
    __shared__ float lu[256], lv[256];
    int tid = threadIdx.x;
    int bid = blockIdx.x;
    // XCD swizzle: bid = cc*64 + g  => all 32 blocks of graph g share bid%8 (same XCD L2)
    int g = bid & 63, cc = bid >> 6, r0 = cc * 32;
    const unsigned short* el = elist + (size_t)g * Ec;
    const float* xg = x + (size_t)g * Nc * FIN;
    if (tid < 256) { lu[tid] = 0.f; lv[tid] = 0.f; }

    // phase A: one (row, 8-dim chunk) per thread, edge loop batched by 8
    {
        int lr = tid >> 4, ch = tid & 15;
        int n = r0 + lr;
        int o0 = off[g * 1032 + n], o1 = off[g * 1032 + n + 1];
        float4 a0 = make_float4(0.f, 0.f, 0.f, 0.f);
        float4 a1 = make_float4(0.f, 0.f, 0.f, 0.f);
        const float* xc = xg + ch * 8;
        int e = o0;
        for (; e + 8 <= o1; e += 8) {
            int s[8];
#pragma unroll
            for (int j = 0; j < 8; ++j) s[j] = el[e + j];
            float4 v0[8], v1[8];
#pragma unroll
            for (int j = 0; j < 8; ++j) {
                const float4* xp = (const float4*)(xc + (size_t)s[j] * FIN);
                v0[j] = xp[0]; v1[j] = xp[1];
            }
#pragma unroll
            for (int j = 0; j < 8; ++j) {
                a0.x += v0[j].x; a0.y += v0[j].y; a0.z += v0[j].z; a0.w += v0[j].w;
                a1.x += v1[j].x; a1.y += v1[j].y; a1.z += v1[j].z; a1.w += v1[j].w;
            }
        }
        for (; e < o1; ++e) {
            const float4* xp = (const float4*)(xc + (size_t)el[e] * FIN);
            float4 v0 = xp[0], v1 = xp[1];
            a0.x += v0.x; a0.y += v0.y; a0.z += v0.z; a0.w += v0.w;
            a1.x += v1.x; a1.y += v1.y; a1.z += v1.z; a1.w += v1.w;
        }
        float iv = invdeg[g * Nc + n];
        float* dp = &aggL[lr * 132 + ch * 8];
        dp[0] = a0.x * iv; dp[1] = a0.y * iv; dp[2] = a0.z * iv; dp[3] = a0.w * iv;
        dp[4] = a1.x * iv; dp[5] = a1.y * iv; dp[6] = a1.z * iv; dp[7] = a1.w * iv;
    }
    // stage own-row x tile (float4)
    for (int i = tid; i < 1024; i += 512) {
        int lr = i >> 5, kq = i & 31;
        *(float4*)&xL[lr * 132 + kq * 4] = *(const float4*)&xg[(size_t)(r0 + lr) * FIN + kq * 4];
    }
    __syncthreads();

    // phase B: 8 waves: mt = w&1 (16-row tile), nh = w>>1 (4 n-tiles each)
    int w = tid >> 6, lane = tid & 63, quad = lane >> 4;
    int mt = w & 1, nh = w >> 1;
    int lrow = mt * 16 + (lane & 15);
    v4f acc[4];
#pragma unroll
    for (int i = 0; i < 4; ++i) acc[i] = (v4f)0.f;
    for (int kc = 0; kc < 8; ++kc) {
        const float* ap = (kc < 4) ? &aggL[lrow * 132 + kc * 32 + quad * 8]
                                   : &xL[lrow * 132 + (kc - 4) * 32 + quad * 8];
        float4 f0 = *(const float4*)ap;
        float4 f1 = *(const float4*)(ap + 4);
        float av[8] = {f0.x, f0.y, f0.z, f0.w, f1.x, f1.y, f1.z, f1.w};
        v8bf aH, aL;
#pragma unroll
        for (int j = 0; j < 8; ++j) {
            __bf16 hb = (__bf16)av[j];
            aH[j] = hb;
            aL[j] = (__bf16)(av[j] - (float)hb);
        }
#pragma unroll
        for (int i = 0; i < 4; ++i) {
            int nt = nh * 4 + i;
            v8bf bH = *(const v8bf*)(pH + ((size_t)(kc * 16 + nt) * 64 + lane) * 8);
            v8bf bL = *(const v8bf*)(pL + ((size_t)(kc * 16 + nt) * 64 + lane) * 8);
            acc[i] = __builtin_amdgcn_mfma_f32_16x16x32_bf16(aH, bH, acc[i], 0, 0, 0);
            acc[i] = __builtin_amdgcn_mfma_f32_16x16x32_bf16(aL, bH, acc[i], 0, 0, 0);
            acc[i] = __builtin_amdgcn_mfma_f32_16x16x32_bf16(aH, bL, acc[i], 0, 0, 0);
        }
    }

    // epilogue: bias+relu; u (cw-weighted) / v column sums. C/D: col=lane&15, row=quad*4+r
    float c4[4];
    int nb = g * Nc + r0 + mt * 16 + quad * 4;
#pragma unroll
    for (int r = 0; r < 4; ++r) c4[r] = cw[nb + r];
#pragma unroll
    for (int i = 0; i < 4; ++i) {
        int col = (nh * 4 + i) * 16 + (lane & 15);
        float bcol = bias[col];
        float su = 0.f, sv = 0.f;
#pragma unroll
        for (int r = 0; r < 4; ++r) {
            float val = fmaxf(acc[i][r] + bcol, 0.f);
            sv += val;
            su += c4[r] * val;
        }
        su += __shfl_xor(su, 16); sv += __shfl_xor(sv, 16);
        su += __shfl_xor(su, 32); sv += __shfl_xor(sv, 32);
        if (quad == 0) { atomicAdd(&lu[col], su); atomicAdd(&lv[col], sv); }
    }
    __syncthreads();
    if (tid < 256) {
        atomicAdd(&uv[g * 512 + tid], lu[tid]);
        atomicAdd(&uv[g * 512 + 256 + tid], lv[tid]);
    }
}

// ---------------- emb = u/N @ Wl2 + bl2 + v/N @ Wr2. 512 thr, K split 2 ----------------
__global__ __launch_bounds__(512) void emb_kernel(
        const float* __restrict__ uv, const float* __restrict__ Wl2,
        const float* __restrict__ bl2, const float* __restrict__ Wr2,
        float* __restrict__ h) {
    __shared__ float s[512];
    __shared__ float r2[512];
    int g = blockIdx.x, tid = threadIdx.x;
    s[tid] = uv[g * 512 + tid] * (1.0f / Nc);
    __syncthreads();
    int col = tid & 255, p = tid >> 8;
    float val = 0.f;
    if (p == 0) { for (int k = 0; k < 256; ++k) val += s[k] * Wl2[(size_t)k * Hc + col]; }
    else        { for (int k = 0; k < 256; ++k) val += s[256 + k] * Wr2[(size_t)k * Hc + col]; }
    r2[tid] = val;
    __syncthreads();
    if (tid < 256) h[g * Hc + tid] = bl2[tid] + r2[tid] + r2[tid + 256];
}

// ---------------- qkv: token x seg, 512 thr, K split 2 ----------------
__global__ __launch_bounds__(512) void qkv_kernel(
        const float* __restrict__ h, const float* __restrict__ Wqkv,
        const float* __restrict__ bqkv, float* __restrict__ qkv, int l) {
    __shared__ float hr[256];
    __shared__ float r2[512];
    int bid = blockIdx.x;            // 64 tokens * 3 segs
    int gi = bid / 3, seg = bid % 3;
    int tid = threadIdx.x;
    if (tid < 256) hr[tid] = h[gi * Hc + tid];
    __syncthreads();
    int col = seg * 256 + (tid & 255);
    int half = tid >> 8;
    const float* W = Wqkv + (size_t)l * Hc * 768;
    float val = 0.f;
    int k0 = half * 128;
    for (int k = 0; k < 128; ++k) val += hr[k0 + k] * W[(size_t)(k0 + k) * 768 + col];
    r2[tid] = val;
    __syncthreads();
    if (tid < 256) qkv[gi * 768 + col] = bqkv[(size_t)l * 768 + col] + r2[tid] + r2[tid + 256];
}

// ---------------- fused attn+proj+ln1+ffn1+ffn2+ln2(+fc): per token, 1024 thr ----------------
#define KVS 516
__global__ __launch_bounds__(1024) void rest_kernel(
        const float* __restrict__ hin, float* __restrict__ hout,
        const float* __restrict__ qkvg,
        const float* __restrict__ Wo, const float* __restrict__ bo,
        const float* __restrict__ s1, const float* __restrict__ b1ln,
        const float* __restrict__ W1, const float* __restrict__ bf1,
        const float* __restrict__ W2, const float* __restrict__ bf2,
        const float* __restrict__ s2, const float* __restrict__ b2ln,
        const float* __restrict__ fcW, const float* __restrict__ fcb,
        float* __restrict__ out, int l, int last) {
    __shared__ float kv[16 * KVS];
    __shared__ float q[256];
    __shared__ float sc[8][17];
    __shared__ float ctx[256];
    __shared__ float r2[512];
    __shared__ float red[256];
    __shared__ float rF[2048];
    __shared__ float fLs[1024];
    __shared__ float h1L[256];
    int t = blockIdx.x, tid = threadIdx.x;
    int b = t >> 4;
    const float* qb = qkvg + (size_t)(b * 16) * 768;
    for (int i = tid; i < 8192; i += 1024) {
        int j = i >> 9, d = i & 511;
        kv[j * KVS + d] = qb[(size_t)j * 768 + 256 + d];
    }
    if (tid < 256) q[tid] = qkvg[(size_t)t * 768 + tid];
    __syncthreads();
    if (tid < 128) {
        int hd = tid >> 4, jj = tid & 15;
        float s = 0.f;
#pragma unroll
        for (int d = 0; d < 32; ++d) s += q[hd * 32 + d] * kv[jj * KVS + hd * 32 + d];
        sc[hd][jj] = s * 0.17677669529663687f;
    }
    __syncthreads();
    if (tid < 8) {
        float m = sc[tid][0];
        for (int j = 1; j < 16; ++j) m = fmaxf(m, sc[tid][j]);
        float e[16], sum = 0.f;
        for (int j = 0; j < 16; ++j) { e[j] = expf(sc[tid][j] - m); sum += e[j]; }
        float inv = 1.0f / sum;
        for (int j = 0; j < 16; ++j) sc[tid][j] = e[j] * inv;
    }
    __syncthreads();
    if (tid < 256) {
        int hd = tid >> 5, d = tid & 31;
        float o = 0.f;
#pragma unroll
        for (int j = 0; j < 16; ++j) o += sc[hd][j] * kv[j * KVS + 256 + hd * 32 + d];
        ctx[tid] = o;
    }
    __syncthreads();
    // proj: K split 2
    if (tid < 512) {
        int col = tid & 255, half = tid >> 8;
        const float* W = Wo + (size_t)l * 65536;
        float pv = 0.f;
        int k0 = half * 128;
        for (int k = 0; k < 128; ++k) pv += ctx[k0 + k] * W[(size_t)(k0 + k) * 256 + col];
        r2[tid] = pv;
    }
    __syncthreads();
    float val = 0.f;
    if (tid < 256) {
        val = hin[(size_t)t * 256 + tid] + bo[(size_t)l * 256 + tid] + r2[tid] + r2[tid + 256];
        red[tid] = val;
    }
    __syncthreads();
    float sm1; TREE256(red, tid, sm1);
    float m1 = sm1 * (1.0f / 256.0f);
    __syncthreads();
    float d1 = val - m1;
    if (tid < 256) red[tid] = d1 * d1;
    __syncthreads();
    float sv1; TREE256(red, tid, sv1);
    float v1 = sv1 * (1.0f / 256.0f);
    if (tid < 256)
        h1L[tid] = d1 * rsqrtf(v1 + EPSc) * s1[(size_t)l * 256 + tid] + b1ln[(size_t)l * 256 + tid];
    __syncthreads();
    // ffn1 (K split 2, 4 colgroups)
#pragma unroll
    for (int pass = 0; pass < 2; ++pass) {
        int pid = pass * 1024 + tid;
        int cg = pid >> 9, ch = pid & 511;
        int col = cg * 256 + (ch & 255), half = ch >> 8;
        const float* W = W1 + (size_t)l * 262144;
        float v = 0.f;
        int k0 = half * 128;
        for (int k = 0; k < 128; ++k) v += h1L[k0 + k] * W[(size_t)(k0 + k) * 1024 + col];
        rF[pid] = v;
    }
    __syncthreads();
    {
        int cg = tid >> 8, c8 = tid & 255;
        fLs[tid] = fmaxf(bf1[(size_t)l * 1024 + tid] + rF[cg * 512 + c8] + rF[cg * 512 + 256 + c8], 0.f);
    }
    __syncthreads();
    // ffn2 (K split 4)
    {
        int col = tid & 255, kq = tid >> 8;
        const float* W = W2 + (size_t)l * 262144;
        float p = 0.f;
        int k0 = kq * 256;
        for (int k = 0; k < 256; ++k) p += fLs[k0 + k] * W[(size_t)(k0 + k) * 256 + col];
        rF[tid] = p;
    }
    __syncthreads();
    float val2 = 0.f;
    if (tid < 256) {
        val2 = h1L[tid] + bf2[(size_t)l * 256 + tid]
             + rF[tid] + rF[tid + 256] + rF[tid + 512] + rF[tid + 768];
        red[tid] = val2;
    }
    __syncthreads();
    float sm2; TREE256(red, tid, sm2);
    float m2 = sm2 * (1.0f / 256.0f);
    __syncthreads();
    float d2 = (tid < 256) ? (val2 - m2) : 0.f;
    if (tid < 256) red[tid] = d2 * d2;
    __syncthreads();
    float sv2; TREE256(red, tid, sv2);
    float var2 = sv2 * (1.0f / 256.0f);
    float hn = 0.f;
    if (tid < 256) {
        hn = d2 * rsqrtf(var2 + EPSc) * s2[(size_t)l * 256 + tid] + b2ln[(size_t)l * 256 + tid];
        hout[(size_t)t * 256 + tid] = hn;
    }
    if (last && (t & 15) == 15) {
        __syncthreads();
        if (tid < 256) red[tid] = hn;
        __syncthreads();
        if (tid < 10) {
            int bb = t >> 4;
            float fv = fcb[tid];
            for (int k = 0; k < 256; ++k) fv += red[k] * fcW[(size_t)k * 10 + tid];
            out[bb * 10 + tid] = fv;
        }
    }
}

extern "C" void kernel_launch(void* const* d_in, const int* in_sizes, int n_in,
                              void* d_out, int out_size, void* d_ws, size_t ws_size,
                              hipStream_t stream) {
    (void)in_sizes; (void)n_in; (void)out_size; (void)ws_size;
    const float* x    = (const float*)d_in[0];
    const int*   ei   = (const int*)d_in[1];
    const float* s1Wl = (const float*)d_in[2];
    const float* s1bl = (const float*)d_in[3];
    const float* s1Wr = (const float*)d_in[4];
    const float* s2Wl = (const float*)d_in[5];
    const float* s2bl = (const float*)d_in[6];
    const float* s2Wr = (const float*)d_in[7];
    const float* Wqkv = (const float*)d_in[8];
    const float* bqkv = (const float*)d_in[9];
    const float* Wo   = (const float*)d_in[10];
    const float* bo   = (const float*)d_in[11];
    const float* ln1s = (const float*)d_in[12];
    const float* ln1b = (const float*)d_in[13];
    const float* W1   = (const float*)d_in[14];
    const float* b1   = (const float*)d_in[15];
    const float* W2   = (const float*)d_in[16];
    const float* b2   = (const float*)d_in[17];
    const float* ln2s = (const float*)d_in[18];
    const float* ln2b = (const float*)d_in[19];
    const float* fcW  = (const float*)d_in[20];
    const float* fcb  = (const float*)d_in[21];

    // workspace layout (total ~3.6 MB)
    char* ws = (char*)d_ws;
    __bf16*         packWH = (__bf16*)(ws + 0);          // 131072
    __bf16*         packWL = (__bf16*)(ws + 131072);     // 131072
    float*          invdeg = (float*)(ws + 262144);      // 262144
    float*          cw     = (float*)(ws + 524288);      // 262144
    int*            off    = (int*)(ws + 786432);        // 264192
    unsigned short* elist  = (unsigned short*)(ws + 1050624); // 2097152
    float*          uv     = (float*)(ws + 3147776);     // 131072
    float*          h      = (float*)(ws + 3278848);     // 65536
    float*          h2     = (float*)(ws + 3344384);     // 65536
    float*          qkvg   = (float*)(ws + 3409920);     // 196608
                                                         // end = 3606528

    pack_w_kernel<<<128, 512, 0, stream>>>(s1Wl, s1Wr, packWH, packWL);
    csr_kernel<<<Gc, 1024, 0, stream>>>(ei, invdeg, cw, off, elist, uv);
    sage_kernel<<<Gc * 32, 512, 0, stream>>>(x, elist, off, invdeg, cw, packWH, packWL, s1bl, uv);
    emb_kernel<<<Gc, 512, 0, stream>>>(uv, s2Wl, s2bl, s2Wr, h);
    qkv_kernel<<<Gc * 3, 512, 0, stream>>>(h, Wqkv, bqkv, qkvg, 0);
    rest_kernel<<<Gc, 1024, 0, stream>>>(h, h2, qkvg, Wo, bo, ln1s, ln1b,
                                         W1, b1, W2, b2, ln2s, ln2b, fcW, fcb,
                                         (float*)d_out, 0, 0);
    qkv_kernel<<<Gc * 3, 512, 0, stream>>>(h2, Wqkv, bqkv, qkvg, 1);
    rest_kernel<<<Gc, 1024, 0, stream>>>(h2, h, qkvg, Wo, bo, ln1s, ln1b,
                                         W1, b1, W2, b2, ln2s, ln2b, fcW, fcb,
                                         (float*)d_out, 1, 1);
}